// Round 10
// baseline (192.226 us; speedup 1.0000x reference)
//
#include <hip/hip_runtime.h>

// MultiHeadAttention: N=4, S=T=2048, E=512, H=8, HD=64. fp32 in/out, bf16 MFMA compute.
// R12: gemm_qkv pipeline fixed — A-loads issued post-barrier (with stageB), 2-deep A reg
// pipeline (rA0 landed / rA1 in flight), per-iter wait = vmcnt(4) lgkmcnt(0) so no wait
// ever covers a just-issued load (R10/R11 drained vmcnt(0) on the A(it+2) loads every
// iteration = exposed HBM latency x16). XCD-local grid + fused f32 A-cast kept.
// attn/merge/gemm_out unchanged. 5 dispatches.

#define DEV __device__ __forceinline__

typedef unsigned short u16;
typedef unsigned int u32;
typedef __bf16 bf16x8 __attribute__((ext_vector_type(8)));
typedef float f32x4 __attribute__((ext_vector_type(4)));

#define MFMA_BF16(A, B, C) __builtin_amdgcn_mfma_f32_16x16x32_bf16(A, B, C, 0, 0, 0)

DEV u16 f2bf(float f) {  // RNE
  u32 u = __builtin_bit_cast(u32, f);
  u += 0x7fffu + ((u >> 16) & 1u);
  return (u16)(u >> 16);
}

// async global->LDS, 16B per lane. LDS dst must be lane-contiguous (wave-uniform base + lane*16).
DEV void cp16(void* l, const void* g) {
  __builtin_amdgcn_global_load_lds(
      (const __attribute__((address_space(1))) u32*)g,
      (__attribute__((address_space(3))) u32*)l, 16, 0, 0);
}

#define WAIT_VM(N) asm volatile("s_waitcnt vmcnt(" #N ")" ::: "memory")
#define WAIT_VM4_LG asm volatile("s_waitcnt vmcnt(4) lgkmcnt(0)" ::: "memory")
#define WAIT_VM8_LG asm volatile("s_waitcnt vmcnt(8) lgkmcnt(0)" ::: "memory")
#define WAIT_VMLG  asm volatile("s_waitcnt vmcnt(0) lgkmcnt(0)" ::: "memory")
#define WAIT_LG    asm volatile("s_waitcnt lgkmcnt(0)" ::: "memory")
#define BARRIER    asm volatile("s_barrier" ::: "memory")

// f32x4 pair -> 8 bf16 (compiler emits v_cvt_pk_bf16_f32; RNE, matches f2bf)
DEV bf16x8 cvt8(float4 a, float4 b) {
  bf16x8 v;
  v[0] = (__bf16)a.x; v[1] = (__bf16)a.y; v[2] = (__bf16)a.z; v[3] = (__bf16)a.w;
  v[4] = (__bf16)b.x; v[5] = (__bf16)b.y; v[6] = (__bf16)b.z; v[7] = (__bf16)b.w;
  return v;
}

// ---------------- weights cast: 4 x 256 blocks ----------------
__global__ __launch_bounds__(256) void cast_w(
    const float* __restrict__ a, const float* __restrict__ b,
    const float* __restrict__ c, const float* __restrict__ d2,
    u16* ao, u16* bo, u16* co, u16* do_) {
  int t = blockIdx.x >> 8;
  const float* s = (t == 0) ? a : (t == 1) ? b : (t == 2) ? c : d2;
  u16* d = (t == 0) ? ao : (t == 1) ? bo : (t == 2) ? co : do_;
  int i = (blockIdx.x & 255) * 256 + threadIdx.x;
  float4 f = ((const float4*)s)[i];
  ushort4 o;
  o.x = f2bf(f.x); o.y = f2bf(f.y); o.z = f2bf(f.z); o.w = f2bf(f.w);
  ((ushort4*)d)[i] = o;
}

// Fused QKV projection: 1D grid 768. b>>8 selects Q/K/V; n0 = ((b>>6)&3)*128 (slow),
// m0 = (b&63)*128 (fast) -> A-strip sharers at stride 64 (same XCD under round-robin).
// A is the f32 input; cast fused into staging. Pipeline (steady state, iter J):
//   [rA0 = A(J+1) landed, rA1 = A(J+2) in flight, B(J+1) in flight]
//   1. ds_write A(J+1) -> As[(J+1)&1]      (rA0 loads landed 2 iters ago)
//   2. ds_read + MFMA tile J
//   3. vmcnt(4) lgkm(0): B(J+1) landed (issued 1 iter ago), A(J+2) stays in flight
//   4. barrier
//   5. stageB(J+2) -> Bs[J&1]; issue A(J+3) loads; rotate rA0<-rA1
__global__ __launch_bounds__(256) void gemm_qkv(
    const float* __restrict__ qf, const float* __restrict__ kf, const float* __restrict__ vf,
    const u16* __restrict__ wq, const u16* __restrict__ wk, const u16* __restrict__ wv,
    const float* __restrict__ bq, const float* __restrict__ bk, const float* __restrict__ bv,
    u16* qp, u16* kp, u16* vtO) {
  __shared__ u16 SH[17408];  // As[8192] | Bs[8192]; epilogue reuses all as Cs[128][136]
  u16* As = SH;
  u16* Bs = SH + 8192;
  const int b = blockIdx.x;
  const int wsel = b >> 8;
  const float* A = (wsel == 0) ? qf : (wsel == 1) ? kf : vf;
  const u16* W = (wsel == 0) ? wq : (wsel == 1) ? wk : wv;
  const float* bias = (wsel == 0) ? bq : (wsel == 1) ? bk : bv;
  const int n0 = ((b >> 6) & 3) * 128, m0 = (b & 63) * 128;
  const int tid = threadIdx.x, lane = tid & 63, wid = tid >> 6;
  const int wm = wid & 1, wn = wid >> 1;
  const int l15 = lane & 15, l4 = lane >> 4;

  // per-thread A staging coords: chunk c0 = tid (rows 0..63), c1 = tid+256 (rows 64..127)
  const int r0 = tid >> 2, kc = (tid & 3) * 8;
  const float* A0 = A + (m0 + r0) * 512 + kc;        // advance by +32 f32 per tile
  const float* A1 = A + (m0 + r0 + 64) * 512 + kc;

  auto stageB = [&](u16* Bsb, int kt) {
#pragma unroll
    for (int i = 0; i < 2; ++i) {
      int c = tid + 256 * i;
      int row = c >> 2, kcb = (c & 3) * 8;
      cp16(&Bsb[c * 8], W + (n0 + row) * 512 + kt + kcb);
    }
  };

  f32x4 acc[4][4] = {};
  {
    // ---- prologue: issue A(0), A(1); B(0), B(1); write A(0); issue A(2) ----
    float4 t00 = *(const float4*)(A0);        // A(0)
    float4 t01 = *(const float4*)(A0 + 4);
    float4 t02 = *(const float4*)(A1);
    float4 t03 = *(const float4*)(A1 + 4);
    float4 rA0a = *(const float4*)(A0 + 32);  // A(1)
    float4 rA0b = *(const float4*)(A0 + 36);
    float4 rA0c = *(const float4*)(A1 + 32);
    float4 rA0d = *(const float4*)(A1 + 36);
    stageB(Bs, 0);
    stageB(Bs + 4096, 32);
    *(bf16x8*)&As[tid * 8] = cvt8(t00, t01);            // implicit wait on A(0)
    *(bf16x8*)&As[(tid + 256) * 8] = cvt8(t02, t03);
    float4 rA1a = *(const float4*)(A0 + 64);  // A(2)
    float4 rA1b = *(const float4*)(A0 + 68);
    float4 rA1c = *(const float4*)(A1 + 64);
    float4 rA1d = *(const float4*)(A1 + 68);
    WAIT_VM8_LG;  // A(1)+B(0) landed; B(1)+A(2) stay in flight; my ds_writes drained
    BARRIER;

    for (int it = 0; it < 16; ++it) {
      // 1. ds_write A(it+1) from rA0 (loads landed >=1 full iteration ago)
      if (it < 15) {
        u16* Ad = As + ((it + 1) & 1) * 4096;
        *(bf16x8*)&Ad[tid * 8] = cvt8(rA0a, rA0b);
        *(bf16x8*)&Ad[(tid + 256) * 8] = cvt8(rA0c, rA0d);
      }
      // 2. ds_read + MFMA on tile it
      const u16* Ac = As + (it & 1) * 4096;
      const u16* Bc = Bs + (it & 1) * 4096;
      bf16x8 af[4], bfr[4];
#pragma unroll
      for (int f = 0; f < 4; ++f) {
        af[f]  = *(const bf16x8*)&Ac[(wm * 64 + f * 16 + l15) * 32 + l4 * 8];
        bfr[f] = *(const bf16x8*)&Bc[(wn * 64 + f * 16 + l15) * 32 + l4 * 8];
      }
      __builtin_amdgcn_s_setprio(1);
#pragma unroll
      for (int fm = 0; fm < 4; ++fm)
#pragma unroll
        for (int fn = 0; fn < 4; ++fn)
          acc[fm][fn] = MFMA_BF16(af[fm], bfr[fn], acc[fm][fn]);
      __builtin_amdgcn_s_setprio(0);
      // 3-5. counted wait, barrier, next-stage issues
      if (it < 15) {
        if (it < 14) { WAIT_VM4_LG; }  // B(it+1) landed; A(it+2) stays in flight
        else         { WAIT_VMLG; }    // tail: only B(15) outstanding
        BARRIER;                       // buf[(it+1)&1] fully ready; buf[it&1] free
        if (it + 2 < 16) stageB(Bs + (it & 1) * 4096, (it + 2) * 32);
        rA0a = rA1a; rA0b = rA1b; rA0c = rA1c; rA0d = rA1d;
        if (it + 3 < 16) {
          const float* P0 = A0 + (it + 3) * 32;
          const float* P1 = A1 + (it + 3) * 32;
          rA1a = *(const float4*)(P0);
          rA1b = *(const float4*)(P0 + 4);
          rA1c = *(const float4*)(P1);
          rA1d = *(const float4*)(P1 + 4);
        }
      }
    }
  }

  if (wsel == 2) {
    // V: stage output tile in LDS transposed to [d_local][t_perm] (stride 136 u16,
    // 16B-aligned rows), then stream out coalesced: vt row segment is 256B contiguous.
    WAIT_LG;  // own ds_reads of the last MFMA done
    BARRIER;  // all waves done with As/Bs -> safe to reuse as Cs
    u16* Cs = SH;
#pragma unroll
    for (int fn = 0; fn < 4; ++fn) {
      int dl = wn * 64 + fn * 16 + l15;          // local out-dim = vt-row within tile
      float bvv = bias[n0 + dl];
#pragma unroll
      for (int fm = 0; fm < 4; ++fm) {
        int trow = wm * 64 + fm * 16 + l4 * 4;   // local t (4 consecutive)
        int t64 = trow & 63;
        int pbase = (trow >> 6) * 64 + ((((t64 >> 5) << 2) | ((t64 >> 2) & 3)) << 3)
                    + (((t64 >> 4) & 1) << 2);
        ushort4 o;
        o.x = f2bf(acc[fm][fn][0] + bvv);
        o.y = f2bf(acc[fm][fn][1] + bvv);
        o.z = f2bf(acc[fm][fn][2] + bvv);
        o.w = f2bf(acc[fm][fn][3] + bvv);
        *(ushort4*)&Cs[dl * 136 + pbase] = o;
      }
    }
    WAIT_LG;  // ds_writes landed
    BARRIER;  // visible to all waves
    const int nb = m0 >> 11, m0loc = m0 & 2047;
#pragma unroll
    for (int i = 0; i < 8; ++i) {
      int f = i * 256 + tid;                     // 2048 16B-chunks, wave = 1KB dense
      int rowd = f >> 4, ch = (f & 15) * 8;
      uint4 x = *(const uint4*)&Cs[rowd * 136 + ch];
      *(uint4*)(vtO + (nb * 512 + n0 + rowd) * 2048 + m0loc + ch) = x;
    }
  } else {
    u16* C = (wsel == 0) ? qp : kp;
    const float osc = (wsel == 0) ? 0.18033688f : 1.0f;  // (1/8)*log2(e) folded into Q
#pragma unroll
    for (int fn = 0; fn < 4; ++fn) {
      int col = n0 + wn * 64 + fn * 16 + l15;
      float bvv = bias[col];
#pragma unroll
      for (int fm = 0; fm < 4; ++fm) {
        int rowb = m0 + wm * 64 + fm * 16 + l4 * 4;
#pragma unroll
        for (int r = 0; r < 4; ++r)
          C[(rowb + r) * 512 + col] = f2bf((acc[fm][fn][r] + bvv) * osc);
      }
    }
  }
}

// Final projection: fp32 out, 64x128 tile, grid (4,128)=512 blocks, counted-wait loop.
__global__ __launch_bounds__(256) void gemm_out(const u16* __restrict__ A,
                                                const u16* __restrict__ W,
                                                const float* __restrict__ bias,
                                                float* __restrict__ C) {
  __shared__ u16 As[2 * 64 * 32];
  __shared__ u16 Bs[2 * 128 * 32];
  const int n0 = blockIdx.x * 128, m0 = blockIdx.y * 64;
  const int tid = threadIdx.x, lane = tid & 63, wid = tid >> 6;
  const int wm = wid & 1, wn = wid >> 1;  // wave tile 32x64
  const int l15 = lane & 15, l4 = lane >> 4;

  auto stage = [&](u16* Asb, u16* Bsb, int kt) {
    {
      int row = tid >> 2, kc = (tid & 3) * 8;
      cp16(&Asb[tid * 8], A + (m0 + row) * 512 + kt + kc);
    }
#pragma unroll
    for (int i = 0; i < 2; ++i) {
      int c = tid + 256 * i;
      int row = c >> 2, kc = (c & 3) * 8;
      cp16(&Bsb[c * 8], W + (n0 + row) * 512 + kt + kc);
    }
  };

  f32x4 acc[2][4] = {};
  stage(As, Bs, 0);
  stage(As + 2048, Bs + 4096, 32);
  WAIT_VM(3);  // tile 0 (3 loads) landed; tile 1 in flight
  BARRIER;
  for (int it = 0; it < 16; ++it) {
    const u16* Ac = As + (it & 1) * 2048;
    const u16* Bc = Bs + (it & 1) * 4096;
    bf16x8 af[2], bfr[4];
#pragma unroll
    for (int f = 0; f < 2; ++f)
      af[f] = *(const bf16x8*)&Ac[(wm * 32 + f * 16 + l15) * 32 + l4 * 8];
#pragma unroll
    for (int f = 0; f < 4; ++f)
      bfr[f] = *(const bf16x8*)&Bc[(wn * 64 + f * 16 + l15) * 32 + l4 * 8];
    __builtin_amdgcn_s_setprio(1);
#pragma unroll
    for (int fm = 0; fm < 2; ++fm)
#pragma unroll
      for (int fn = 0; fn < 4; ++fn)
        acc[fm][fn] = MFMA_BF16(af[fm], bfr[fn], acc[fm][fn]);
    __builtin_amdgcn_s_setprio(0);
    if (it < 15) {
      WAIT_VMLG;
      BARRIER;
      if (it + 2 < 16)
        stage(As + (it & 1) * 2048, Bs + (it & 1) * 4096, (it + 2) * 32);
    }
  }

#pragma unroll
  for (int fn = 0; fn < 4; ++fn) {
    int col = n0 + wn * 64 + fn * 16 + l15;
    float bvv = bias[col];
#pragma unroll
    for (int fm = 0; fm < 2; ++fm) {
      int rowb = m0 + wm * 32 + fm * 16 + l4 * 4;
#pragma unroll
      for (int r = 0; r < 4; ++r)
        C[(rowb + r) * 512 + col] = acc[fm][fn][r] + bvv;
    }
  }
}

// ---------------- Flash attention, causal, split-T, Q in registers -----------------
// Split-T heavy-first grid (1536 blocks), fixed-reference softmax, 32KB LDS.
__global__ __launch_bounds__(256) void attn_kernel(const u16* __restrict__ Qg,
                                                   const u16* __restrict__ Kg,
                                                   const u16* __restrict__ Vt,
                                                   u16* __restrict__ Yg,
                                                   float* __restrict__ Opart,
                                                   float* __restrict__ Lpart) {
  __shared__ u16 Ks[128 * 64];   // K tile [t][d], source-swizzled chunks   (16 KB)
  __shared__ u16 Vts[64 * 128];  // V^T tile [d][t_perm], swizzled chunks   (16 KB)

  const int bid = blockIdx.x;
  int qt, nh, it0 = 0, half = 0;
  bool split;
  if (bid < 512) {
    qt = 16 + (bid >> 5); nh = bid & 31; split = true;          // heavy primary
  } else if (bid < 576) {
    int i = bid - 512; qt = 14 + (i >> 5); nh = i & 31; split = false;
  } else if (bid < 640) {
    int i = bid - 576; qt = 30 + (i >> 5); nh = i & 31; it0 = 8; half = 1; split = true;
  } else {
    int g = bid - 640, c = 7 - (g >> 7), k = g & 127;
    if (k < 64) { qt = 2 * c - 2 + (k >> 5); nh = k & 31; split = false; }
    else { int k2 = k - 64; qt = 2 * c + 14 + (k2 >> 5); nh = k2 & 31; it0 = 8; half = 1; split = true; }
  }
  const int nt = (qt >> 1) + 1;
  const int itEnd = (split && half == 0) ? 8 : nt;

  const int n = nh >> 3, h = nh & 7;
  const int tid = threadIdx.x, lane = tid & 63, w = tid >> 6;
  const int l15 = lane & 15, l4 = lane >> 4;
  const int s0 = qt * 64;

  const u16* Kb = Kg + n * 2048 * 512 + h * 64;
  const u16* Vb = Vt + nh * 64 * 2048;

  // ---- Q fragments direct to registers (2 dwordx4 per lane; compiler waits) ----
  const int qr = w * 16 + l15;
  const u16* qptr = Qg + (n * 2048 + s0 + qr) * 512 + h * 64;
  bf16x8 qf0 = __builtin_bit_cast(bf16x8, *(const uint4*)(qptr + l4 * 8));
  bf16x8 qf1 = __builtin_bit_cast(bf16x8, *(const uint4*)(qptr + 32 + l4 * 8));

  // hoisted per-lane staging addresses (advance by constant stride per tile-step)
  const u16* kSrc[4];
  const u16* vSrc[4];
  int kDst[4], vDst[4];
#pragma unroll
  for (int i = 0; i < 4; ++i) {
    int c = tid + 256 * i;
    int t = c >> 3, dg = (c & 7) ^ (t & 7);
    kSrc[i] = Kb + (it0 * 128 + t) * 512 + dg * 8;
    kDst[i] = c * 8;
    int d = c >> 4, x = c & 15;
    vSrc[i] = Vb + d * 2048 + it0 * 128 + ((x ^ (d & 15)) * 8);
    vDst[i] = c * 8;
  }

  // ---- prologue: issue K(it0) (4), V(it0) (4) ----
#pragma unroll
  for (int i = 0; i < 4; ++i) { cp16(&Ks[kDst[i]], kSrc[i]); kSrc[i] += 128 * 512; }
#pragma unroll
  for (int i = 0; i < 4; ++i) { cp16(&Vts[vDst[i]], vSrc[i]); vSrc[i] += 128; }

  WAIT_VM(4);  // K(it0) landed (V(it0) in flight)
  BARRIER;

  f32x4 accO[4] = {};
  f32x4 lacc = {};                  // deferred l accumulation (reduced in epilogue)
  const int sgl = s0 + w * 16 + l15;

  for (int it = it0; it < itEnd; ++it) {
    const int t0 = it * 128;
    const bool more = (it + 1 < itEnd);

    // ---- S^T = K Q^T : 8 frags along t (rows), cols m = l15. Q pre-scaled. ----
    f32x4 st[8];
    __builtin_amdgcn_s_setprio(1);
#pragma unroll
    for (int fn = 0; fn < 8; ++fn) {
      int tr = fn * 16 + l15;
      bf16x8 k0 = *(const bf16x8*)&Ks[tr * 64 + ((l4 ^ (tr & 7)) * 8)];
      bf16x8 k1 = *(const bf16x8*)&Ks[tr * 64 + (((4 + l4) ^ (tr & 7)) * 8)];
      f32x4 a = {};
      a = MFMA_BF16(k0, qf0, a);
      st[fn] = MFMA_BF16(k1, qf1, a);
    }
    __builtin_amdgcn_s_setprio(0);

    WAIT_VMLG;  // own Ks reads done + own V(it) chunks landed
    BARRIER;    // cross-wave: Ks free to overwrite, Vts fully ready
    if (more) {
#pragma unroll
      for (int i = 0; i < 4; ++i) { cp16(&Ks[kDst[i]], kSrc[i]); kSrc[i] += 128 * 512; }
    }

    // ---- softmax numerator, fixed reference m=0: P = exp2(score) ----
    const bool diag = (t0 + 128 > s0);  // true only on the tile's diagonal step
    if (diag) {
#pragma unroll
      for (int fn = 0; fn < 8; ++fn)
#pragma unroll
        for (int r = 0; r < 4; ++r) {
          int tg = t0 + fn * 16 + l4 * 4 + r;
          if (tg > sgl) st[fn][r] = -1e30f;
        }
    }
#pragma unroll
    for (int fn = 0; fn < 8; ++fn)
#pragma unroll
      for (int r = 0; r < 4; ++r)
        st[fn][r] = __builtin_amdgcn_exp2f(st[fn][r]);
    {
      f32x4 s4 = st[0] + st[1];
      s4 += st[2] + st[3];
      s4 += st[4] + st[5];
      s4 += st[6] + st[7];
      lacc += s4;
    }

    // ---- P -> bf16 A-frags; pa[ks] slot j = P[m][ks*32+16*(j>>2)+l4*4+(j&3)] ----
    bf16x8 pa[4];
#pragma unroll
    for (int ks = 0; ks < 4; ++ks) {
      bf16x8 t;
      t[0] = (__bf16)st[2 * ks][0];     t[1] = (__bf16)st[2 * ks][1];
      t[2] = (__bf16)st[2 * ks][2];     t[3] = (__bf16)st[2 * ks][3];
      t[4] = (__bf16)st[2 * ks + 1][0]; t[5] = (__bf16)st[2 * ks + 1][1];
      t[6] = (__bf16)st[2 * ks + 1][2]; t[7] = (__bf16)st[2 * ks + 1][3];
      pa[ks] = t;
    }

    // ---- O += P V : B-frag = one b128; permuted vt layout matches pa's k-relabel ----
    __builtin_amdgcn_s_setprio(1);
#pragma unroll
    for (int ks = 0; ks < 4; ++ks) {
#pragma unroll
      for (int fd = 0; fd < 4; ++fd) {
        int d = fd * 16 + l15;
        bf16x8 bv = *(const bf16x8*)&Vts[d * 128 + (((ks * 4 + l4) ^ l15) * 8)];
        accO[fd] = MFMA_BF16(pa[ks], bv, accO[fd]);
      }
    }
    __builtin_amdgcn_s_setprio(0);

    if (more) {
      WAIT_VMLG;  // own Vts reads done + own K(it+1) chunks landed
      BARRIER;    // cross-wave: Vts free to overwrite, Ks(it+1) fully ready
#pragma unroll
      for (int i = 0; i < 4; ++i) { cp16(&Vts[vDst[i]], vSrc[i]); vSrc[i] += 128; }
    }
  }

  // ---- epilogue: reduce l (deferred), then direct write or partial dump ----
  float lr = lacc[0] + lacc[1] + lacc[2] + lacc[3];
  lr += __shfl_xor(lr, 16);
  lr += __shfl_xor(lr, 32);

  if (!split) {
    float lO[4];
#pragma unroll
    for (int r = 0; r < 4; ++r) lO[r] = __shfl(lr, (lane & 48) | (l4 * 4 + r));
#pragma unroll
    for (int fd = 0; fd < 4; ++fd)
#pragma unroll
      for (int r = 0; r < 4; ++r) {
        int row = s0 + w * 16 + l4 * 4 + r;
        int col = h * 64 + fd * 16 + l15;
        Yg[(n * 2048 + row) * 512 + col] = f2bf(accO[fd][r] / lO[r]);
      }
  } else {
    const int p = (qt - 16) * 32 + nh;
    float* Ob = Opart + (p * 2 + half) * 4096;
#pragma unroll
    for (int fd = 0; fd < 4; ++fd)
#pragma unroll
      for (int r = 0; r < 4; ++r)
        Ob[(fd * 4 + r) * 256 + tid] = accO[fd][r];  // fully coalesced 1KB stores
    if (l4 == 0) Lpart[(p * 2 + half) * 64 + w * 16 + l15] = lr;
  }
}

// ---------------- merge: O = O1+O2, l = l1+l2 (fixed-reference -> pure adds) --------
__global__ __launch_bounds__(256) void merge_o(const float* __restrict__ Opart,
                                               const float* __restrict__ Lpart,
                                               u16* __restrict__ Yg) {
  const int p = blockIdx.x;
  const int qt = 16 + (p >> 5), nh = p & 31;
  const int n = nh >> 3, h = nh & 7, s0 = qt * 64;
  const int tid = threadIdx.x, lane = tid & 63, w = tid >> 6;
  const int l15 = lane & 15, l4 = lane >> 4;
  const float* O1 = Opart + p * 8192;
  const float* O2 = O1 + 4096;
  const float* L1 = Lpart + p * 128;
  const float* L2 = L1 + 64;
  float lO[4];
#pragma unroll
  for (int r = 0; r < 4; ++r) {
    int row = w * 16 + l4 * 4 + r;
    lO[r] = L1[row] + L2[row];
  }
#pragma unroll
  for (int fd = 0; fd < 4; ++fd)
#pragma unroll
    for (int r = 0; r < 4; ++r) {
      float o = O1[(fd * 4 + r) * 256 + tid] + O2[(fd * 4 + r) * 256 + tid];
      int row = s0 + w * 16 + l4 * 4 + r;
      int col = h * 64 + fd * 16 + l15;
      Yg[(n * 2048 + row) * 512 + col] = f2bf(o / lO[r]);
    }
}

extern "C" void kernel_launch(void* const* d_in, const int* in_sizes, int n_in,
                              void* d_out, int out_size, void* d_ws, size_t ws_size,
                              hipStream_t stream) {
  (void)in_sizes; (void)n_in; (void)out_size; (void)ws_size;
  const float* query = (const float*)d_in[0];
  const float* key_  = (const float*)d_in[1];
  const float* value = (const float*)d_in[2];
  // d_in[3] = attn_mask (tril) — causal, applied structurally
  const float* Wq = (const float*)d_in[4];
  const float* bq = (const float*)d_in[5];
  const float* Wk = (const float*)d_in[6];
  const float* bk = (const float*)d_in[7];
  const float* Wv = (const float*)d_in[8];
  const float* bv = (const float*)d_in[9];
  const float* Wp = (const float*)d_in[10];
  const float* bp = (const float*)d_in[11];

  char* ws = (char*)d_ws;  // 50 MB total
  u16* y   = (u16*)(ws);                // 8 MB (attn output)
  u16* kx  = (u16*)(ws + 8388608);      // 8 MB; O-partials region (with vx)
  u16* vx  = (u16*)(ws + 16777216);     // 8 MB
  u16* wqx = (u16*)(ws + 25165824);     // 512 KB; L-partials region in attn
  u16* wkx = (u16*)(ws + 25690112);
  u16* wvx = (u16*)(ws + 26214400);
  u16* wpx = (u16*)(ws + 26738688);
  u16* qp  = (u16*)(ws + 27262976);     // 8 MB
  u16* kp  = (u16*)(ws + 35651584);     // 8 MB
  u16* vt  = (u16*)(ws + 44040192);     // 8 MB; V^T written directly by gemm_qkv
  float* Opart = (float*)kx;            // 512 pairs x 2 x 4096 f32 = 16 MB (kx+vx)
  float* Lpart = (float*)wqx;           // 1024 x 64 f32 = 256 KB (within wqx region)

  cast_w<<<1024, 256, 0, stream>>>(Wq, Wk, Wv, Wp, wqx, wkx, wvx, wpx);
  gemm_qkv<<<768, 256, 0, stream>>>(query, key_, value, wqx, wkx, wvx,
                                    bq, bk, bv, qp, kp, vt);
  attn_kernel<<<1536, 256, 0, stream>>>(qp, kp, vt, y, Opart, Lpart);
  merge_o<<<512, 256, 0, stream>>>(Opart, Lpart, y);
  gemm_out<<<dim3(4, 128), 256, 0, stream>>>(y, wpx, bp, (float*)d_out);
}

// Round 12
// 186.228 us; speedup vs baseline: 1.0322x; 1.0322x over previous
//
#include <hip/hip_runtime.h>

// MultiHeadAttention: N=4, S=T=2048, E=512, H=8, HD=64. fp32 in/out, bf16 MFMA compute.
// R14 = R13 with the prologue B-staging offset bug fixed (B(1) -> Bs+4096, was Bs+2048,
// which corrupted buffer 0 and left buffer 1 uninitialized -> NaN).
// gemm_qkv: 64x128 tile, 1536 blocks, 24KB LDS -> 5-6 blocks/CU so cross-block TLP hides
// the per-iter load/barrier latency (R11/R12: latency-bound at 12-15% occupancy).
// Fused f32 A-cast, XCD-local A map. attn/merge/gemm_out unchanged. 5 dispatches.

#define DEV __device__ __forceinline__

typedef unsigned short u16;
typedef unsigned int u32;
typedef __bf16 bf16x8 __attribute__((ext_vector_type(8)));
typedef float f32x4 __attribute__((ext_vector_type(4)));

#define MFMA_BF16(A, B, C) __builtin_amdgcn_mfma_f32_16x16x32_bf16(A, B, C, 0, 0, 0)

DEV u16 f2bf(float f) {  // RNE
  u32 u = __builtin_bit_cast(u32, f);
  u += 0x7fffu + ((u >> 16) & 1u);
  return (u16)(u >> 16);
}

// async global->LDS, 16B per lane. LDS dst must be lane-contiguous (wave-uniform base + lane*16).
DEV void cp16(void* l, const void* g) {
  __builtin_amdgcn_global_load_lds(
      (const __attribute__((address_space(1))) u32*)g,
      (__attribute__((address_space(3))) u32*)l, 16, 0, 0);
}

#define WAIT_VM(N) asm volatile("s_waitcnt vmcnt(" #N ")" ::: "memory")
#define WAIT_VM2_LG asm volatile("s_waitcnt vmcnt(2) lgkmcnt(0)" ::: "memory")
#define WAIT_VMLG  asm volatile("s_waitcnt vmcnt(0) lgkmcnt(0)" ::: "memory")
#define WAIT_LG    asm volatile("s_waitcnt lgkmcnt(0)" ::: "memory")
#define BARRIER    asm volatile("s_barrier" ::: "memory")

// f32x4 pair -> 8 bf16 (compiler emits v_cvt_pk_bf16_f32; RNE, matches f2bf)
DEV bf16x8 cvt8(float4 a, float4 b) {
  bf16x8 v;
  v[0] = (__bf16)a.x; v[1] = (__bf16)a.y; v[2] = (__bf16)a.z; v[3] = (__bf16)a.w;
  v[4] = (__bf16)b.x; v[5] = (__bf16)b.y; v[6] = (__bf16)b.z; v[7] = (__bf16)b.w;
  return v;
}

// ---------------- weights cast: 4 x 256 blocks ----------------
__global__ __launch_bounds__(256) void cast_w(
    const float* __restrict__ a, const float* __restrict__ b,
    const float* __restrict__ c, const float* __restrict__ d2,
    u16* ao, u16* bo, u16* co, u16* do_) {
  int t = blockIdx.x >> 8;
  const float* s = (t == 0) ? a : (t == 1) ? b : (t == 2) ? c : d2;
  u16* d = (t == 0) ? ao : (t == 1) ? bo : (t == 2) ? co : do_;
  int i = (blockIdx.x & 255) * 256 + threadIdx.x;
  float4 f = ((const float4*)s)[i];
  ushort4 o;
  o.x = f2bf(f.x); o.y = f2bf(f.y); o.z = f2bf(f.z); o.w = f2bf(f.w);
  ((ushort4*)d)[i] = o;
}

// Fused QKV projection: 1D grid 1536. wsel = b>>9; idx = b&511; n0 = ((idx>>7)&3)*128,
// m0 = (idx&127)*64. A-strip sharers (same m0, 4 n0) at stride 128 == 0 mod 8 -> same XCD.
// Tile 64(M) x 128(N), 4 waves of 32x64, BK=32, 16 K-iters, double-buffered LDS.
// LDS map (u16 units): As buf0 @0, buf1 @2048; Bs buf0 @4096, buf1 @8192. Total 12288 u16.
// A operand = f32 input, cast fused: per thread 1 chunk (2 float4 loads -> cvt -> ds_write),
// p/q 2-deep register pipeline. B via cp16. Q output pre-scaled by (1/8)*log2(e).
// V output LDS-transposed to vt[nh*64+d][t_perm] with coalesced dwordx4 stores.
__global__ __launch_bounds__(256) void gemm_qkv(
    const float* __restrict__ qf, const float* __restrict__ kf, const float* __restrict__ vf,
    const u16* __restrict__ wq, const u16* __restrict__ wk, const u16* __restrict__ wv,
    const float* __restrict__ bq, const float* __restrict__ bk, const float* __restrict__ bv,
    u16* qp, u16* kp, u16* vtO) {
  __shared__ u16 SH[12288];  // 24576 B; V-epilogue reuses as Cs[128][72]
  u16* As = SH;              // per buf: 64 rows x 32 k = 2048 u16
  u16* Bs = SH + 4096;       // per buf: 128 rows x 32 k = 4096 u16
  const int b = blockIdx.x;
  const int wsel = b >> 9;
  const int idx = b & 511;
  const float* A = (wsel == 0) ? qf : (wsel == 1) ? kf : vf;
  const u16* W = (wsel == 0) ? wq : (wsel == 1) ? wk : wv;
  const float* bias = (wsel == 0) ? bq : (wsel == 1) ? bk : bv;
  const int n0 = ((idx >> 7) & 3) * 128, m0 = (idx & 127) * 64;
  const int tid = threadIdx.x, lane = tid & 63, wid = tid >> 6;
  const int wm = wid & 1, wn = wid >> 1;  // wave tile: 32(M) x 64(N)
  const int l15 = lane & 15, l4 = lane >> 4;

  // per-thread A chunk: row = tid>>2 (0..63), kc = (tid&3)*8
  const float* A0 = A + (m0 + (tid >> 2)) * 512 + (tid & 3) * 8;  // +32 f32 per K-tile

  auto stageB = [&](u16* Bsb, int kt) {
#pragma unroll
    for (int i = 0; i < 2; ++i) {
      int c = tid + 256 * i;
      int row = c >> 2, kcb = (c & 3) * 8;
      cp16(&Bsb[c * 8], W + (n0 + row) * 512 + kt + kcb);
    }
  };

  f32x4 acc[2][4] = {};
  {
    // ---- prologue: A(0)->write, p=A(1), q=A(2); B(0)->buf0, B(1)->buf1 ----
    float4 t0a = *(const float4*)(A0);
    float4 t0b = *(const float4*)(A0 + 4);
    float4 pA  = *(const float4*)(A0 + 32);
    float4 pB  = *(const float4*)(A0 + 36);
    float4 qA  = *(const float4*)(A0 + 64);
    float4 qB  = *(const float4*)(A0 + 68);
    stageB(Bs, 0);
    stageB(Bs + 4096, 32);                     // FIX: buf1 is at +4096 u16 (was +2048)
    *(bf16x8*)&As[tid * 8] = cvt8(t0a, t0b);   // compiler waits t0*
    WAIT_VM2_LG;  // p,q,B(0) landed; B(1) (newest 2) in flight; my ds_write drained
    BARRIER;

    for (int it = 0; it < 16; ++it) {
      if (it < 15)   // ds_write A(it+1) from p (landed)
        *(bf16x8*)&As[((it + 1) & 1) * 2048 + tid * 8] = cvt8(pA, pB);
      const u16* Ac = As + (it & 1) * 2048;
      const u16* Bc = Bs + (it & 1) * 4096;
      bf16x8 af[2], bfr[4];
#pragma unroll
      for (int f = 0; f < 2; ++f)
        af[f] = *(const bf16x8*)&Ac[(wm * 32 + f * 16 + l15) * 32 + l4 * 8];
#pragma unroll
      for (int f = 0; f < 4; ++f)
        bfr[f] = *(const bf16x8*)&Bc[(wn * 64 + f * 16 + l15) * 32 + l4 * 8];
      __builtin_amdgcn_s_setprio(1);
#pragma unroll
      for (int fm = 0; fm < 2; ++fm)
#pragma unroll
        for (int fn = 0; fn < 4; ++fn)
          acc[fm][fn] = MFMA_BF16(af[fm], bfr[fn], acc[fm][fn]);
      __builtin_amdgcn_s_setprio(0);
      if (it < 15) {
        WAIT_VMLG;  // B(it+1) + q landed; own ds ops done (TLP across 5-6 blocks hides this)
        BARRIER;    // buf[(it+1)&1] ready; buf[it&1] free
        if (it + 2 < 16) stageB(Bs + (it & 1) * 4096, (it + 2) * 32);
        pA = qA; pB = qB;  // q landed (drained above)
        if (it + 3 < 16) {
          const float* P = A0 + (it + 3) * 32;
          qA = *(const float4*)(P);
          qB = *(const float4*)(P + 4);
        }
      }
    }
  }

  if (wsel == 2) {
    // V: stage 64t x 128d output tile transposed into Cs[d_local 0..127][t_perm 0..63]
    // (stride 72 u16 = 144B, 16B-aligned rows), then stream out fully coalesced.
    WAIT_LG;  // own ds_reads of last MFMA done
    BARRIER;  // all waves done with As/Bs -> reuse as Cs
    u16* Cs = SH;
#pragma unroll
    for (int fn = 0; fn < 4; ++fn) {
      int dl = wn * 64 + fn * 16 + l15;          // local out-dim 0..127
      float bvv = bias[n0 + dl];
#pragma unroll
      for (int fm = 0; fm < 2; ++fm) {
        int t64 = wm * 32 + fm * 16 + l4 * 4;    // local t 0..63 (4 consecutive)
        // permuted pos within the 64-t block: 4-aligned group -> contiguous 4
        int pbase = ((((t64 >> 5) << 2) | ((t64 >> 2) & 3)) << 3) + (((t64 >> 4) & 1) << 2);
        ushort4 o;
        o.x = f2bf(acc[fm][fn][0] + bvv);
        o.y = f2bf(acc[fm][fn][1] + bvv);
        o.z = f2bf(acc[fm][fn][2] + bvv);
        o.w = f2bf(acc[fm][fn][3] + bvv);
        *(ushort4*)&Cs[dl * 72 + pbase] = o;
      }
    }
    WAIT_LG;
    BARRIER;
    const int nb = m0 >> 11, tt = (m0 & 2047) >> 6;
#pragma unroll
    for (int i = 0; i < 4; ++i) {
      int f = i * 256 + tid;                     // 1024 16B-chunks
      int rowd = f >> 3, ch = (f & 7) * 8;
      uint4 x = *(const uint4*)&Cs[rowd * 72 + ch];
      int gl = n0 + rowd, h = gl >> 6, d = gl & 63;
      *(uint4*)(vtO + ((nb * 8 + h) * 64 + d) * 2048 + tt * 64 + ch) = x;
    }
  } else {
    u16* C = (wsel == 0) ? qp : kp;
    const float osc = (wsel == 0) ? 0.18033688f : 1.0f;  // (1/8)*log2(e) folded into Q
#pragma unroll
    for (int fn = 0; fn < 4; ++fn) {
      int col = n0 + wn * 64 + fn * 16 + l15;
      float bvv = bias[col];
#pragma unroll
      for (int fm = 0; fm < 2; ++fm) {
        int rowb = m0 + wm * 32 + fm * 16 + l4 * 4;
#pragma unroll
        for (int r = 0; r < 4; ++r)
          C[(rowb + r) * 512 + col] = f2bf((acc[fm][fn][r] + bvv) * osc);
      }
    }
  }
}

// Final projection: fp32 out, 64x128 tile, grid (4,128)=512 blocks, counted-wait loop.
__global__ __launch_bounds__(256) void gemm_out(const u16* __restrict__ A,
                                                const u16* __restrict__ W,
                                                const float* __restrict__ bias,
                                                float* __restrict__ C) {
  __shared__ u16 As[2 * 64 * 32];
  __shared__ u16 Bs[2 * 128 * 32];
  const int n0 = blockIdx.x * 128, m0 = blockIdx.y * 64;
  const int tid = threadIdx.x, lane = tid & 63, wid = tid >> 6;
  const int wm = wid & 1, wn = wid >> 1;  // wave tile 32x64
  const int l15 = lane & 15, l4 = lane >> 4;

  auto stage = [&](u16* Asb, u16* Bsb, int kt) {
    {
      int row = tid >> 2, kc = (tid & 3) * 8;
      cp16(&Asb[tid * 8], A + (m0 + row) * 512 + kt + kc);
    }
#pragma unroll
    for (int i = 0; i < 2; ++i) {
      int c = tid + 256 * i;
      int row = c >> 2, kc = (c & 3) * 8;
      cp16(&Bsb[c * 8], W + (n0 + row) * 512 + kt + kc);
    }
  };

  f32x4 acc[2][4] = {};
  stage(As, Bs, 0);
  stage(As + 2048, Bs + 4096, 32);
  WAIT_VM(3);  // tile 0 (3 loads) landed; tile 1 in flight
  BARRIER;
  for (int it = 0; it < 16; ++it) {
    const u16* Ac = As + (it & 1) * 2048;
    const u16* Bc = Bs + (it & 1) * 4096;
    bf16x8 af[2], bfr[4];
#pragma unroll
    for (int f = 0; f < 2; ++f)
      af[f] = *(const bf16x8*)&Ac[(wm * 32 + f * 16 + l15) * 32 + l4 * 8];
#pragma unroll
    for (int f = 0; f < 4; ++f)
      bfr[f] = *(const bf16x8*)&Bc[(wn * 64 + f * 16 + l15) * 32 + l4 * 8];
    __builtin_amdgcn_s_setprio(1);
#pragma unroll
    for (int fm = 0; fm < 2; ++fm)
#pragma unroll
      for (int fn = 0; fn < 4; ++fn)
        acc[fm][fn] = MFMA_BF16(af[fm], bfr[fn], acc[fm][fn]);
    __builtin_amdgcn_s_setprio(0);
    if (it < 15) {
      WAIT_VMLG;
      BARRIER;
      if (it + 2 < 16)
        stage(As + (it & 1) * 2048, Bs + (it & 1) * 4096, (it + 2) * 32);
    }
  }

#pragma unroll
  for (int fn = 0; fn < 4; ++fn) {
    int col = n0 + wn * 64 + fn * 16 + l15;
    float bvv = bias[col];
#pragma unroll
    for (int fm = 0; fm < 2; ++fm) {
      int rowb = m0 + wm * 32 + fm * 16 + l4 * 4;
#pragma unroll
      for (int r = 0; r < 4; ++r)
        C[(rowb + r) * 512 + col] = acc[fm][fn][r] + bvv;
    }
  }
}

// ---------------- Flash attention, causal, split-T, Q in registers -----------------
// Split-T heavy-first grid (1536 blocks), fixed-reference softmax, 32KB LDS.
__global__ __launch_bounds__(256) void attn_kernel(const u16* __restrict__ Qg,
                                                   const u16* __restrict__ Kg,
                                                   const u16* __restrict__ Vt,
                                                   u16* __restrict__ Yg,
                                                   float* __restrict__ Opart,
                                                   float* __restrict__ Lpart) {
  __shared__ u16 Ks[128 * 64];   // K tile [t][d], source-swizzled chunks   (16 KB)
  __shared__ u16 Vts[64 * 128];  // V^T tile [d][t_perm], swizzled chunks   (16 KB)

  const int bid = blockIdx.x;
  int qt, nh, it0 = 0, half = 0;
  bool split;
  if (bid < 512) {
    qt = 16 + (bid >> 5); nh = bid & 31; split = true;          // heavy primary
  } else if (bid < 576) {
    int i = bid - 512; qt = 14 + (i >> 5); nh = i & 31; split = false;
  } else if (bid < 640) {
    int i = bid - 576; qt = 30 + (i >> 5); nh = i & 31; it0 = 8; half = 1; split = true;
  } else {
    int g = bid - 640, c = 7 - (g >> 7), k = g & 127;
    if (k < 64) { qt = 2 * c - 2 + (k >> 5); nh = k & 31; split = false; }
    else { int k2 = k - 64; qt = 2 * c + 14 + (k2 >> 5); nh = k2 & 31; it0 = 8; half = 1; split = true; }
  }
  const int nt = (qt >> 1) + 1;
  const int itEnd = (split && half == 0) ? 8 : nt;

  const int n = nh >> 3, h = nh & 7;
  const int tid = threadIdx.x, lane = tid & 63, w = tid >> 6;
  const int l15 = lane & 15, l4 = lane >> 4;
  const int s0 = qt * 64;

  const u16* Kb = Kg + n * 2048 * 512 + h * 64;
  const u16* Vb = Vt + nh * 64 * 2048;

  // ---- Q fragments direct to registers (2 dwordx4 per lane; compiler waits) ----
  const int qr = w * 16 + l15;
  const u16* qptr = Qg + (n * 2048 + s0 + qr) * 512 + h * 64;
  bf16x8 qf0 = __builtin_bit_cast(bf16x8, *(const uint4*)(qptr + l4 * 8));
  bf16x8 qf1 = __builtin_bit_cast(bf16x8, *(const uint4*)(qptr + 32 + l4 * 8));

  // hoisted per-lane staging addresses (advance by constant stride per tile-step)
  const u16* kSrc[4];
  const u16* vSrc[4];
  int kDst[4], vDst[4];
#pragma unroll
  for (int i = 0; i < 4; ++i) {
    int c = tid + 256 * i;
    int t = c >> 3, dg = (c & 7) ^ (t & 7);
    kSrc[i] = Kb + (it0 * 128 + t) * 512 + dg * 8;
    kDst[i] = c * 8;
    int d = c >> 4, x = c & 15;
    vSrc[i] = Vb + d * 2048 + it0 * 128 + ((x ^ (d & 15)) * 8);
    vDst[i] = c * 8;
  }

  // ---- prologue: issue K(it0) (4), V(it0) (4) ----
#pragma unroll
  for (int i = 0; i < 4; ++i) { cp16(&Ks[kDst[i]], kSrc[i]); kSrc[i] += 128 * 512; }
#pragma unroll
  for (int i = 0; i < 4; ++i) { cp16(&Vts[vDst[i]], vSrc[i]); vSrc[i] += 128; }

  WAIT_VM(4);  // K(it0) landed (V(it0) in flight)
  BARRIER;

  f32x4 accO[4] = {};
  f32x4 lacc = {};                  // deferred l accumulation (reduced in epilogue)
  const int sgl = s0 + w * 16 + l15;

  for (int it = it0; it < itEnd; ++it) {
    const int t0 = it * 128;
    const bool more = (it + 1 < itEnd);

    // ---- S^T = K Q^T : 8 frags along t (rows), cols m = l15. Q pre-scaled. ----
    f32x4 st[8];
    __builtin_amdgcn_s_setprio(1);
#pragma unroll
    for (int fn = 0; fn < 8; ++fn) {
      int tr = fn * 16 + l15;
      bf16x8 k0 = *(const bf16x8*)&Ks[tr * 64 + ((l4 ^ (tr & 7)) * 8)];
      bf16x8 k1 = *(const bf16x8*)&Ks[tr * 64 + (((4 + l4) ^ (tr & 7)) * 8)];
      f32x4 a = {};
      a = MFMA_BF16(k0, qf0, a);
      st[fn] = MFMA_BF16(k1, qf1, a);
    }
    __builtin_amdgcn_s_setprio(0);

    WAIT_VMLG;  // own Ks reads done + own V(it) chunks landed
    BARRIER;    // cross-wave: Ks free to overwrite, Vts fully ready
    if (more) {
#pragma unroll
      for (int i = 0; i < 4; ++i) { cp16(&Ks[kDst[i]], kSrc[i]); kSrc[i] += 128 * 512; }
    }

    // ---- softmax numerator, fixed reference m=0: P = exp2(score) ----
    const bool diag = (t0 + 128 > s0);  // true only on the tile's diagonal step
    if (diag) {
#pragma unroll
      for (int fn = 0; fn < 8; ++fn)
#pragma unroll
        for (int r = 0; r < 4; ++r) {
          int tg = t0 + fn * 16 + l4 * 4 + r;
          if (tg > sgl) st[fn][r] = -1e30f;
        }
    }
#pragma unroll
    for (int fn = 0; fn < 8; ++fn)
#pragma unroll
      for (int r = 0; r < 4; ++r)
        st[fn][r] = __builtin_amdgcn_exp2f(st[fn][r]);
    {
      f32x4 s4 = st[0] + st[1];
      s4 += st[2] + st[3];
      s4 += st[4] + st[5];
      s4 += st[6] + st[7];
      lacc += s4;
    }

    // ---- P -> bf16 A-frags; pa[ks] slot j = P[m][ks*32+16*(j>>2)+l4*4+(j&3)] ----
    bf16x8 pa[4];
#pragma unroll
    for (int ks = 0; ks < 4; ++ks) {
      bf16x8 t;
      t[0] = (__bf16)st[2 * ks][0];     t[1] = (__bf16)st[2 * ks][1];
      t[2] = (__bf16)st[2 * ks][2];     t[3] = (__bf16)st[2 * ks][3];
      t[4] = (__bf16)st[2 * ks + 1][0]; t[5] = (__bf16)st[2 * ks + 1][1];
      t[6] = (__bf16)st[2 * ks + 1][2]; t[7] = (__bf16)st[2 * ks + 1][3];
      pa[ks] = t;
    }

    // ---- O += P V : B-frag = one b128; permuted vt layout matches pa's k-relabel ----
    __builtin_amdgcn_s_setprio(1);
#pragma unroll
    for (int ks = 0; ks < 4; ++ks) {
#pragma unroll
      for (int fd = 0; fd < 4; ++fd) {
        int d = fd * 16 + l15;
        bf16x8 bv = *(const bf16x8*)&Vts[d * 128 + (((ks * 4 + l4) ^ l15) * 8)];
        accO[fd] = MFMA_BF16(pa[ks], bv, accO[fd]);
      }
    }
    __builtin_amdgcn_s_setprio(0);

    if (more) {
      WAIT_VMLG;  // own Vts reads done + own K(it+1) chunks landed
      BARRIER;    // cross-wave: Vts free to overwrite, Ks(it+1) fully ready
#pragma unroll
      for (int i = 0; i < 4; ++i) { cp16(&Vts[vDst[i]], vSrc[i]); vSrc[i] += 128; }
    }
  }

  // ---- epilogue: reduce l (deferred), then direct write or partial dump ----
  float lr = lacc[0] + lacc[1] + lacc[2] + lacc[3];
  lr += __shfl_xor(lr, 16);
  lr += __shfl_xor(lr, 32);

  if (!split) {
    float lO[4];
#pragma unroll
    for (int r = 0; r < 4; ++r) lO[r] = __shfl(lr, (lane & 48) | (l4 * 4 + r));
#pragma unroll
    for (int fd = 0; fd < 4; ++fd)
#pragma unroll
      for (int r = 0; r < 4; ++r) {
        int row = s0 + w * 16 + l4 * 4 + r;
        int col = h * 64 + fd * 16 + l15;
        Yg[(n * 2048 + row) * 512 + col] = f2bf(accO[fd][r] / lO[r]);
      }
  } else {
    const int p = (qt - 16) * 32 + nh;
    float* Ob = Opart + (p * 2 + half) * 4096;
#pragma unroll
    for (int fd = 0; fd < 4; ++fd)
#pragma unroll
      for (int r = 0; r < 4; ++r)
        Ob[(fd * 4 + r) * 256 + tid] = accO[fd][r];  // fully coalesced 1KB stores
    if (l4 == 0) Lpart[(p * 2 + half) * 64 + w * 16 + l15] = lr;
  }
}

// ---------------- merge: O = O1+O2, l = l1+l2 (fixed-reference -> pure adds) --------
__global__ __launch_bounds__(256) void merge_o(const float* __restrict__ Opart,
                                               const float* __restrict__ Lpart,
                                               u16* __restrict__ Yg) {
  const int p = blockIdx.x;
  const int qt = 16 + (p >> 5), nh = p & 31;
  const int n = nh >> 3, h = nh & 7, s0 = qt * 64;
  const int tid = threadIdx.x, lane = tid & 63, w = tid >> 6;
  const int l15 = lane & 15, l4 = lane >> 4;
  const float* O1 = Opart + p * 8192;
  const float* O2 = O1 + 4096;
  const float* L1 = Lpart + p * 128;
  const float* L2 = L1 + 64;
  float lO[4];
#pragma unroll
  for (int r = 0; r < 4; ++r) {
    int row = w * 16 + l4 * 4 + r;
    lO[r] = L1[row] + L2[row];
  }
#pragma unroll
  for (int fd = 0; fd < 4; ++fd)
#pragma unroll
    for (int r = 0; r < 4; ++r) {
      float o = O1[(fd * 4 + r) * 256 + tid] + O2[(fd * 4 + r) * 256 + tid];
      int row = s0 + w * 16 + l4 * 4 + r;
      int col = h * 64 + fd * 16 + l15;
      Yg[(n * 2048 + row) * 512 + col] = f2bf(o / lO[r]);
    }
}

extern "C" void kernel_launch(void* const* d_in, const int* in_sizes, int n_in,
                              void* d_out, int out_size, void* d_ws, size_t ws_size,
                              hipStream_t stream) {
  (void)in_sizes; (void)n_in; (void)out_size; (void)ws_size;
  const float* query = (const float*)d_in[0];
  const float* key_  = (const float*)d_in[1];
  const float* value = (const float*)d_in[2];
  // d_in[3] = attn_mask (tril) — causal, applied structurally
  const float* Wq = (const float*)d_in[4];
  const float* bq = (const float*)d_in[5];
  const float* Wk = (const float*)d_in[6];
  const float* bk = (const float*)d_in[7];
  const float* Wv = (const float*)d_in[8];
  const float* bv = (const float*)d_in[9];
  const float* Wp = (const float*)d_in[10];
  const float* bp = (const float*)d_in[11];

  char* ws = (char*)d_ws;  // 50 MB total
  u16* y   = (u16*)(ws);                // 8 MB (attn output)
  u16* kx  = (u16*)(ws + 8388608);      // 8 MB; O-partials region (with vx)
  u16* vx  = (u16*)(ws + 16777216);     // 8 MB
  u16* wqx = (u16*)(ws + 25165824);     // 512 KB; L-partials region in attn
  u16* wkx = (u16*)(ws + 25690112);
  u16* wvx = (u16*)(ws + 26214400);
  u16* wpx = (u16*)(ws + 26738688);
  u16* qp  = (u16*)(ws + 27262976);     // 8 MB
  u16* kp  = (u16*)(ws + 35651584);     // 8 MB
  u16* vt  = (u16*)(ws + 44040192);     // 8 MB; V^T written directly by gemm_qkv
  float* Opart = (float*)kx;            // 512 pairs x 2 x 4096 f32 = 16 MB (kx+vx)
  float* Lpart = (float*)wqx;           // 1024 x 64 f32 = 256 KB (within wqx region)

  cast_w<<<1024, 256, 0, stream>>>(Wq, Wk, Wv, Wp, wqx, wkx, wvx, wpx);
  gemm_qkv<<<1536, 256, 0, stream>>>(query, key_, value, wqx, wkx, wvx,
                                     bq, bk, bv, qp, kp, vt);
  attn_kernel<<<1536, 256, 0, stream>>>(qp, kp, vt, y, Opart, Lpart);
  merge_o<<<512, 256, 0, stream>>>(Opart, Lpart, y);
  gemm_out<<<dim3(4, 128), 256, 0, stream>>>(y, wpx, bp, (float*)d_out);
}